// Round 8
// baseline (206.989 us; speedup 1.0000x reference)
//
#include <hip/hip_runtime.h>

#define T_DIM 1024
#define B_DIM 16
#define D_DIM 512
#define K_W   31
#define PAD   15

// ===========================================================================
// ALL numeric ops are f32 with NO fma contraction and numpy-sequential
// reduction order, to bit-match the harness's strict-sequential f32 np ref.
// Rounds 5-7 PASSED with absmax 0.0 — do NOT change rounding/order/precision:
// f64 accuracy FLIPS a borderline spike (rounds 1-4, absmax 0.998046875).
// ===========================================================================

// ---------------------------------------------------------------------------
// K1: pointwise GEMM, f32, strict d-ascending accumulation, no FMA.
// R8: (a) 128e x 64tau tiles -> 1024 blocks = 4/CU (R7 grid was 512 = 2/CU,
// capping occupancy at 19.7%); (b) LDS strides S_E=146, S_T=66 (≡2 mod 8 so
// 4*S ≡ 8 mod 32): the staging writes' kq now spreads over banks
// {0,8,16,24} -> 2-way worst (free, m136). R7's 8-way WRITE conflict
// (4*S ≡ 0 mod 32) was the real source of SQ_LDS_BANK_CONFLICT=2.3e7 —
// the read skew (kept) didn't move it. Arithmetic order identical.
// ---------------------------------------------------------------------------
#define S_E 146
#define S_T 66
__global__ __launch_bounds__(256, 4)
void pw_gemm(const float* __restrict__ inp, const float* __restrict__ w_pw,
             const float* __restrict__ b_pw, float* __restrict__ Yw,
             int tau0, int tau1, int NTW)
{
#pragma clang fp contract(off)
    __shared__ float Es[32 * S_E];   // [k][skew(e_local)]  128 e
    __shared__ float Ts[32 * S_T];   // [k][tau_local]      64 tau

    const int tid = threadIdx.x;
    const int e0  = blockIdx.x * 128;
    int tg0 = tau0 + blockIdx.y * 64;            // tau tile base
    if (tg0 + 64 > tau1) {                       // shift last tile; overlap
        int s = tau1 - 64;                       // writes identical values
        tg0 = (s > tau0) ? s : tau0;
    }
    const int b  = blockIdx.z;
    const int rt = tid >> 4;                     // tau-sub 0..15 (4 tau each)
    const int ce = tid & 15;                     // e-sub   0..15 (8 e each)
    const int eoff = ce * 8 + ((ce >> 2) << 2);  // skewed read base

    float acc[4][8];
#pragma unroll
    for (int i = 0; i < 4; ++i)
#pragma unroll
        for (int j = 0; j < 8; ++j) acc[i][j] = 0.0f;

    for (int k0 = 0; k0 < D_DIM; k0 += 32) {     // strict ascending d blocks
        float4 av[4], xv[2];
#pragma unroll
        for (int i = 0; i < 4; ++i) {            // Es: 128 rows x 8 chunks
            int cid = tid + 256 * i;             // 0..1023
            int row = cid >> 3;                  // 0..127
            int kq  = cid & 7;
            av[i] = *(const float4*)&w_pw[(size_t)(e0 + row) * D_DIM + k0 + kq * 4];
        }
#pragma unroll
        for (int i = 0; i < 2; ++i) {            // Ts: 64 rows x 8 chunks
            int cid = tid + 256 * i;             // 0..511
            int row = cid >> 3;                  // 0..63
            int kq  = cid & 7;
            int trow = tg0 + row;
            if (trow > T_DIM - 1) trow = T_DIM - 1;   // clamp; stores guarded
            xv[i] = *(const float4*)&inp[(size_t)trow * (B_DIM * D_DIM)
                                         + (size_t)b * D_DIM + k0 + kq * 4];
        }
        __syncthreads();
#pragma unroll
        for (int i = 0; i < 4; ++i) {
            int cid = tid + 256 * i;
            int row = cid >> 3;
            int kq  = cid & 7;
            int srow = row + ((row >> 5) << 2);  // skew(e)
            Es[(kq * 4 + 0) * S_E + srow] = av[i].x;
            Es[(kq * 4 + 1) * S_E + srow] = av[i].y;
            Es[(kq * 4 + 2) * S_E + srow] = av[i].z;
            Es[(kq * 4 + 3) * S_E + srow] = av[i].w;
        }
#pragma unroll
        for (int i = 0; i < 2; ++i) {
            int cid = tid + 256 * i;
            int row = cid >> 3;
            int kq  = cid & 7;
            Ts[(kq * 4 + 0) * S_T + row] = xv[i].x;
            Ts[(kq * 4 + 1) * S_T + row] = xv[i].y;
            Ts[(kq * 4 + 2) * S_T + row] = xv[i].z;
            Ts[(kq * 4 + 3) * S_T + row] = xv[i].w;
        }
        __syncthreads();

#pragma unroll 8
        for (int kk = 0; kk < 32; ++kk) {        // strict ascending d
            float4 tf  = *(const float4*)&Ts[kk * S_T + rt * 4];
            float4 ef0 = *(const float4*)&Es[kk * S_E + eoff];
            float4 ef1 = *(const float4*)&Es[kk * S_E + eoff + 4];
            float a[4] = {tf.x, tf.y, tf.z, tf.w};
            float x[8] = {ef0.x, ef0.y, ef0.z, ef0.w, ef1.x, ef1.y, ef1.z, ef1.w};
#pragma unroll
            for (int i = 0; i < 4; ++i)
#pragma unroll
                for (int j = 0; j < 8; ++j)
                    acc[i][j] = __fadd_rn(acc[i][j], __fmul_rn(a[i], x[j]));
        }
    }

    float bias[8];
#pragma unroll
    for (int j = 0; j < 8; ++j) bias[j] = b_pw[e0 + ce * 8 + j];

#pragma unroll
    for (int i = 0; i < 4; ++i) {
        int tau = tg0 + rt * 4 + i;
        if (tau < tau1) {
            float* yrow = Yw + ((size_t)b * NTW + (tau - tau0)) * D_DIM + e0 + ce * 8;
#pragma unroll
            for (int j = 0; j < 8; ++j)
                yrow[j] = __fadd_rn(acc[i][j], bias[j]);
        }
    }
}

// ---------------------------------------------------------------------------
// K2: depthwise conv, f32, strict k-ascending, no FMA, zero padding.
// (byte-identical to rounds 5-7 — proven bit-exact)
// ---------------------------------------------------------------------------
__global__ __launch_bounds__(512, 1)
void dw_conv(const float* __restrict__ Yw, const float* __restrict__ w_dw,
             float* __restrict__ Zw, int t0, int tau0, int NTW)
{
#pragma clang fp contract(off)
    const int d  = threadIdx.x;              // 0..511
    const int tb = blockIdx.x * 8;           // t offset within pass
    const int b  = blockIdx.y;

    float wd[K_W];
#pragma unroll
    for (int k = 0; k < K_W; ++k) wd[k] = w_dw[d * K_W + k];

    const float* ybase = Yw + (size_t)b * NTW * D_DIM + d;

    float yw[38];
#pragma unroll
    for (int i = 0; i < 38; ++i) {
        int tau = t0 + tb - PAD + i;
        yw[i] = (tau >= 0 && tau < T_DIM)
              ? ybase[(size_t)(tau - tau0) * D_DIM] : 0.0f;
    }

#pragma unroll
    for (int j = 0; j < 8; ++j) {
        float z = 0.0f;
#pragma unroll
        for (int k = 0; k < K_W; ++k)        // strict ascending k
            z = __fadd_rn(z, __fmul_rn(wd[k], yw[j + k]));
        Zw[((size_t)(tb + j) * B_DIM + b) * D_DIM + d] = z;
    }
}

// ---------------------------------------------------------------------------
// K3: EXACT sequential LIF scan, f32, numpy op-for-op. z-loads only; packed
// u32 spike bitmasks; 32-step double buffer. (byte-identical to round 7)
// ---------------------------------------------------------------------------
__global__ __launch_bounds__(64, 1)
void lif_scan(const float* __restrict__ Zw, unsigned* __restrict__ sw,
              float* __restrict__ vst, int L, int first)
{
#pragma clang fp contract(off)
    const int lane = threadIdx.x;
    const int b    = blockIdx.x >> 3;                 // 0..15
    const int d    = ((blockIdx.x & 7) << 6) + lane;  // 0..511
    const int gi   = b * D_DIM + d;

    float v = first ? 0.0f : vst[gi];

    const float* zp = Zw + (size_t)b * D_DIM + d;
    unsigned*    wp = sw + gi;                        // + (t>>5)*B*D
    const size_t st = (size_t)B_DIM * D_DIM;
    const int Lm1 = L - 1;

    float zA[32], zB[32];
#pragma unroll
    for (int j = 0; j < 32; ++j) zA[j] = zp[(size_t)j * st];   // L >= 64

    for (int tb = 0; tb < L; tb += 64) {     // L is a multiple of 64
#pragma unroll
        for (int j = 0; j < 32; ++j) {       // issue steps tb+32..tb+63
            int t = tb + 32 + j; t = (t > Lm1) ? Lm1 : t;
            zB[j] = zp[(size_t)t * st];
        }
        unsigned m = 0;
#pragma unroll
        for (int j = 0; j < 32; ++j) {       // consume steps tb..tb+31
            v = __fadd_rn(__fmul_rn(v, 0.5f), zA[j]);
            const bool sp = (v >= 1.0f);
            m |= (sp ? (1u << j) : 0u);
            v = __fmul_rn(v, sp ? 0.0f : 1.0f);   // mirrors np v*(1-s)
        }
        wp[(size_t)(tb >> 5) * st] = m;
#pragma unroll
        for (int j = 0; j < 32; ++j) {       // issue steps tb+64..tb+95
            int t = tb + 64 + j; t = (t > Lm1) ? Lm1 : t;
            zA[j] = zp[(size_t)t * st];
        }
        m = 0;
#pragma unroll
        for (int j = 0; j < 32; ++j) {       // consume steps tb+32..tb+63
            v = __fadd_rn(__fmul_rn(v, 0.5f), zB[j]);
            const bool sp = (v >= 1.0f);
            m |= (sp ? (1u << j) : 0u);
            v = __fmul_rn(v, sp ? 0.0f : 1.0f);
        }
        wp[(size_t)((tb >> 5) + 1) * st] = m;
    }
    vst[gi] = v;
}

// ---------------------------------------------------------------------------
// K4: out[t,b,d] = fl(s + inp[t,b,d]), s = spike bit. (identical to round 7)
// ---------------------------------------------------------------------------
__global__ __launch_bounds__(256, 4)
void spike_add(const unsigned* __restrict__ sw, const float* __restrict__ inp,
               float* __restrict__ out, int t0, int L)
{
#pragma clang fp contract(off)
    const size_t n4 = (size_t)L * B_DIM * D_DIM / 4;
    const float4* ip = (const float4*)(inp + (size_t)t0 * B_DIM * D_DIM);
    float4*       op = (float4*)(out + (size_t)t0 * B_DIM * D_DIM);
    const size_t stride = (size_t)gridDim.x * blockDim.x;

    for (size_t i = (size_t)blockIdx.x * blockDim.x + threadIdx.x;
         i < n4; i += stride) {
        const size_t e    = i * 4;           // element index within pass
        const size_t trel = e >> 13;         // / (B*D = 8192)
        const size_t r    = e & 8191;
        const uint4 w = *(const uint4*)(sw + ((trel >> 5) << 13) + r);
        const unsigned sh = (unsigned)trel & 31u;
        const float4 x = ip[i];
        float4 o;
        o.x = __fadd_rn((float)((w.x >> sh) & 1u), x.x);
        o.y = __fadd_rn((float)((w.y >> sh) & 1u), x.y);
        o.z = __fadd_rn((float)((w.z >> sh) & 1u), x.z);
        o.w = __fadd_rn((float)((w.w >> sh) & 1u), x.w);
        op[i] = o;
    }
}

// ---------------------------------------------------------------------------
// Pass-windowed driver. Spike words overlay the (dead-after-dw_conv) Yw
// region — no extra ws needed. L from ws_size (launch-time constant).
// ---------------------------------------------------------------------------
extern "C" void kernel_launch(void* const* d_in, const int* in_sizes, int n_in,
                              void* d_out, int out_size, void* d_ws, size_t ws_size,
                              hipStream_t stream)
{
    const float* inp  = (const float*)d_in[0];   // (T,B,D)
    const float* w_pw = (const float*)d_in[1];   // (D,D)
    const float* b_pw = (const float*)d_in[2];   // (D)
    const float* w_dw = (const float*)d_in[3];   // (D,K)
    float* out = (float*)d_out;

    auto need = [](int L) -> size_t {
        int ntw = (L + 30 > T_DIM) ? T_DIM : (L + 30);
        return ((size_t)ntw + (size_t)L + 1) * (B_DIM * D_DIM * sizeof(float));
    };
    int L = 64;
    if      (ws_size >= need(1024)) L = 1024;
    else if (ws_size >= need(512))  L = 512;
    else if (ws_size >= need(256))  L = 256;
    else if (ws_size >= need(128))  L = 128;

    const int NTWmax = (L + 30 > T_DIM) ? T_DIM : (L + 30);
    float* Yw  = (float*)d_ws;
    float* Zw  = Yw + (size_t)NTWmax * B_DIM * D_DIM;
    float* vst = Zw + (size_t)L * B_DIM * D_DIM;
    unsigned* sw = (unsigned*)Yw;                // overlay: Yw dead after dw_conv

    const int P = T_DIM / L;
    for (int p = 0; p < P; ++p) {
        const int t0   = p * L;
        const int t1   = t0 + L;
        const int tau0 = (t0 - PAD > 0) ? (t0 - PAD) : 0;
        const int tau1 = (t1 + PAD < T_DIM) ? (t1 + PAD) : T_DIM;
        const int NTW  = tau1 - tau0;

        dim3 g1(D_DIM / 128, (NTW + 63) / 64, B_DIM);
        pw_gemm<<<g1, 256, 0, stream>>>(inp, w_pw, b_pw, Yw, tau0, tau1, NTW);

        dim3 g2(L / 8, B_DIM);
        dw_conv<<<g2, 512, 0, stream>>>(Yw, w_dw, Zw, t0, tau0, NTW);

        lif_scan<<<128, 64, 0, stream>>>(Zw, sw, vst, L, p == 0);

        spike_add<<<2048, 256, 0, stream>>>(sw, inp, out, t0, L);
    }
}

// Round 9
// 193.074 us; speedup vs baseline: 1.0721x; 1.0721x over previous
//
#include <hip/hip_runtime.h>

#define T_DIM 1024
#define B_DIM 16
#define D_DIM 512
#define K_W   31
#define PAD   15

// ===========================================================================
// ALL numeric ops are f32 with NO fma contraction and numpy-sequential
// reduction order, to bit-match the harness's strict-sequential f32 np ref.
// Rounds 5-8 PASSED with absmax 0.0 — do NOT change rounding/order/precision:
// f64 accuracy FLIPS a borderline spike (rounds 1-4, absmax 0.998046875).
// ===========================================================================

// ---------------------------------------------------------------------------
// K1: pointwise GEMM, f32, strict d-ascending accumulation, no FMA.
// R9: R7's 128e x 128tau tile (beat R8's split) + DOUBLE-BUFFERED LDS:
// one barrier per k0-step (was 2), global prefetch for k0+32 issued before
// compute so HBM latency hides under the 32-kk math, LDS-write of the next
// tile goes to buf^1 (disjoint from the buffer being read -> no 2nd barrier).
// Strides S_E=146 / S_T=130 (4*S = 8 mod 32) spread the staging writes'
// kq over banks {0,8,16,24} -> 2-way worst (free, m136). R8 evidence: the
// VALU pipe is ~77% of the 109us roofline; the gap is barrier/staging
// serialization, which this removes. Arithmetic order identical.
// ---------------------------------------------------------------------------
#define S_E 146
#define S_T 130
__global__ __launch_bounds__(256, 2)
void pw_gemm(const float* __restrict__ inp, const float* __restrict__ w_pw,
             const float* __restrict__ b_pw, float* __restrict__ Yw,
             int tau0, int tau1, int NTW)
{
#pragma clang fp contract(off)
    __shared__ float Es[2][32 * S_E];   // [buf][k][skew(e_local)] 128 e
    __shared__ float Ts[2][32 * S_T];   // [buf][k][tau_local]     128 tau

    const int tid = threadIdx.x;
    const int e0  = blockIdx.x * 128;
    int tg0 = tau0 + blockIdx.y * 128;           // tau tile base
    if (tg0 + 128 > tau1) {                      // shift last tile; overlap
        int s = tau1 - 128;                      // writes identical values
        tg0 = (s > tau0) ? s : tau0;
    }
    const int b  = blockIdx.z;
    const int rt = tid >> 4;                     // tau-sub 0..15 (8 tau each)
    const int ce = tid & 15;                     // e-sub   0..15 (8 e each)
    const int eoff = ce * 8 + ((ce >> 2) << 2);  // skewed read base

    // per-thread staging indices (256 threads cover 128 rows x 8 kq chunks
    // in 4 slices for Es, 4 slices for Ts)
    float acc[8][8];
#pragma unroll
    for (int i = 0; i < 8; ++i)
#pragma unroll
        for (int j = 0; j < 8; ++j) acc[i][j] = 0.0f;

    float4 av[4], xv[4];

    // ---- prologue: load k0=0 tile and stage into buf 0
#pragma unroll
    for (int i = 0; i < 4; ++i) {
        int cid = tid + 256 * i;
        int row = cid >> 3;
        int kq  = cid & 7;
        int trow = tg0 + row;
        if (trow > T_DIM - 1) trow = T_DIM - 1;
        av[i] = *(const float4*)&w_pw[(size_t)(e0 + row) * D_DIM + kq * 4];
        xv[i] = *(const float4*)&inp[(size_t)trow * (B_DIM * D_DIM)
                                     + (size_t)b * D_DIM + kq * 4];
    }
#pragma unroll
    for (int i = 0; i < 4; ++i) {
        int cid = tid + 256 * i;
        int row = cid >> 3;
        int kq  = cid & 7;
        int srow = row + ((row >> 5) << 2);      // skew(e)
        Es[0][(kq * 4 + 0) * S_E + srow] = av[i].x;
        Es[0][(kq * 4 + 1) * S_E + srow] = av[i].y;
        Es[0][(kq * 4 + 2) * S_E + srow] = av[i].z;
        Es[0][(kq * 4 + 3) * S_E + srow] = av[i].w;
        Ts[0][(kq * 4 + 0) * S_T + row] = xv[i].x;
        Ts[0][(kq * 4 + 1) * S_T + row] = xv[i].y;
        Ts[0][(kq * 4 + 2) * S_T + row] = xv[i].z;
        Ts[0][(kq * 4 + 3) * S_T + row] = xv[i].w;
    }

    int cur = 0;
    for (int k0 = 0; k0 < D_DIM; k0 += 32) {     // strict ascending d blocks
        __syncthreads();                         // buf[cur] ready for all

        const bool has_next = (k0 + 32 < D_DIM);
        if (has_next) {                          // issue next tile's globals
#pragma unroll
            for (int i = 0; i < 4; ++i) {
                int cid = tid + 256 * i;
                int row = cid >> 3;
                int kq  = cid & 7;
                int trow = tg0 + row;
                if (trow > T_DIM - 1) trow = T_DIM - 1;
                av[i] = *(const float4*)&w_pw[(size_t)(e0 + row) * D_DIM
                                              + k0 + 32 + kq * 4];
                xv[i] = *(const float4*)&inp[(size_t)trow * (B_DIM * D_DIM)
                                             + (size_t)b * D_DIM + k0 + 32 + kq * 4];
            }
        }

#pragma unroll 8
        for (int kk = 0; kk < 32; ++kk) {        // strict ascending d
            float4 tf0 = *(const float4*)&Ts[cur][kk * S_T + rt * 8];
            float4 tf1 = *(const float4*)&Ts[cur][kk * S_T + rt * 8 + 4];
            float4 ef0 = *(const float4*)&Es[cur][kk * S_E + eoff];
            float4 ef1 = *(const float4*)&Es[cur][kk * S_E + eoff + 4];
            float a[8] = {tf0.x, tf0.y, tf0.z, tf0.w, tf1.x, tf1.y, tf1.z, tf1.w};
            float x[8] = {ef0.x, ef0.y, ef0.z, ef0.w, ef1.x, ef1.y, ef1.z, ef1.w};
#pragma unroll
            for (int i = 0; i < 8; ++i)
#pragma unroll
                for (int j = 0; j < 8; ++j)
                    acc[i][j] = __fadd_rn(acc[i][j], __fmul_rn(a[i], x[j]));
        }

        if (has_next) {                          // stage into the other buffer
            const int nxt = cur ^ 1;
#pragma unroll
            for (int i = 0; i < 4; ++i) {
                int cid = tid + 256 * i;
                int row = cid >> 3;
                int kq  = cid & 7;
                int srow = row + ((row >> 5) << 2);
                Es[nxt][(kq * 4 + 0) * S_E + srow] = av[i].x;
                Es[nxt][(kq * 4 + 1) * S_E + srow] = av[i].y;
                Es[nxt][(kq * 4 + 2) * S_E + srow] = av[i].z;
                Es[nxt][(kq * 4 + 3) * S_E + srow] = av[i].w;
                Ts[nxt][(kq * 4 + 0) * S_T + row] = xv[i].x;
                Ts[nxt][(kq * 4 + 1) * S_T + row] = xv[i].y;
                Ts[nxt][(kq * 4 + 2) * S_T + row] = xv[i].z;
                Ts[nxt][(kq * 4 + 3) * S_T + row] = xv[i].w;
            }
            cur = nxt;
        }
    }

    float bias[8];
#pragma unroll
    for (int j = 0; j < 8; ++j) bias[j] = b_pw[e0 + ce * 8 + j];

#pragma unroll
    for (int i = 0; i < 8; ++i) {
        int tau = tg0 + rt * 8 + i;
        if (tau < tau1) {
            float* yrow = Yw + ((size_t)b * NTW + (tau - tau0)) * D_DIM + e0 + ce * 8;
#pragma unroll
            for (int j = 0; j < 8; ++j)
                yrow[j] = __fadd_rn(acc[i][j], bias[j]);
        }
    }
}

// ---------------------------------------------------------------------------
// K2: depthwise conv, f32, strict k-ascending, no FMA, zero padding.
// (byte-identical to rounds 5-8 — proven bit-exact)
// ---------------------------------------------------------------------------
__global__ __launch_bounds__(512, 1)
void dw_conv(const float* __restrict__ Yw, const float* __restrict__ w_dw,
             float* __restrict__ Zw, int t0, int tau0, int NTW)
{
#pragma clang fp contract(off)
    const int d  = threadIdx.x;              // 0..511
    const int tb = blockIdx.x * 8;           // t offset within pass
    const int b  = blockIdx.y;

    float wd[K_W];
#pragma unroll
    for (int k = 0; k < K_W; ++k) wd[k] = w_dw[d * K_W + k];

    const float* ybase = Yw + (size_t)b * NTW * D_DIM + d;

    float yw[38];
#pragma unroll
    for (int i = 0; i < 38; ++i) {
        int tau = t0 + tb - PAD + i;
        yw[i] = (tau >= 0 && tau < T_DIM)
              ? ybase[(size_t)(tau - tau0) * D_DIM] : 0.0f;
    }

#pragma unroll
    for (int j = 0; j < 8; ++j) {
        float z = 0.0f;
#pragma unroll
        for (int k = 0; k < K_W; ++k)        // strict ascending k
            z = __fadd_rn(z, __fmul_rn(wd[k], yw[j + k]));
        Zw[((size_t)(tb + j) * B_DIM + b) * D_DIM + d] = z;
    }
}

// ---------------------------------------------------------------------------
// K3: EXACT sequential LIF scan, f32, numpy op-for-op. z-loads only; packed
// u32 spike bitmasks; 32-step double buffer. (byte-identical to round 7)
// ---------------------------------------------------------------------------
__global__ __launch_bounds__(64, 1)
void lif_scan(const float* __restrict__ Zw, unsigned* __restrict__ sw,
              float* __restrict__ vst, int L, int first)
{
#pragma clang fp contract(off)
    const int lane = threadIdx.x;
    const int b    = blockIdx.x >> 3;                 // 0..15
    const int d    = ((blockIdx.x & 7) << 6) + lane;  // 0..511
    const int gi   = b * D_DIM + d;

    float v = first ? 0.0f : vst[gi];

    const float* zp = Zw + (size_t)b * D_DIM + d;
    unsigned*    wp = sw + gi;                        // + (t>>5)*B*D
    const size_t st = (size_t)B_DIM * D_DIM;
    const int Lm1 = L - 1;

    float zA[32], zB[32];
#pragma unroll
    for (int j = 0; j < 32; ++j) zA[j] = zp[(size_t)j * st];   // L >= 64

    for (int tb = 0; tb < L; tb += 64) {     // L is a multiple of 64
#pragma unroll
        for (int j = 0; j < 32; ++j) {       // issue steps tb+32..tb+63
            int t = tb + 32 + j; t = (t > Lm1) ? Lm1 : t;
            zB[j] = zp[(size_t)t * st];
        }
        unsigned m = 0;
#pragma unroll
        for (int j = 0; j < 32; ++j) {       // consume steps tb..tb+31
            v = __fadd_rn(__fmul_rn(v, 0.5f), zA[j]);
            const bool sp = (v >= 1.0f);
            m |= (sp ? (1u << j) : 0u);
            v = __fmul_rn(v, sp ? 0.0f : 1.0f);   // mirrors np v*(1-s)
        }
        wp[(size_t)(tb >> 5) * st] = m;
#pragma unroll
        for (int j = 0; j < 32; ++j) {       // issue steps tb+64..tb+95
            int t = tb + 64 + j; t = (t > Lm1) ? Lm1 : t;
            zA[j] = zp[(size_t)t * st];
        }
        m = 0;
#pragma unroll
        for (int j = 0; j < 32; ++j) {       // consume steps tb+32..tb+63
            v = __fadd_rn(__fmul_rn(v, 0.5f), zB[j]);
            const bool sp = (v >= 1.0f);
            m |= (sp ? (1u << j) : 0u);
            v = __fmul_rn(v, sp ? 0.0f : 1.0f);
        }
        wp[(size_t)((tb >> 5) + 1) * st] = m;
    }
    vst[gi] = v;
}

// ---------------------------------------------------------------------------
// K4: out[t,b,d] = fl(s + inp[t,b,d]), s = spike bit. (identical to round 7)
// ---------------------------------------------------------------------------
__global__ __launch_bounds__(256, 4)
void spike_add(const unsigned* __restrict__ sw, const float* __restrict__ inp,
               float* __restrict__ out, int t0, int L)
{
#pragma clang fp contract(off)
    const size_t n4 = (size_t)L * B_DIM * D_DIM / 4;
    const float4* ip = (const float4*)(inp + (size_t)t0 * B_DIM * D_DIM);
    float4*       op = (float4*)(out + (size_t)t0 * B_DIM * D_DIM);
    const size_t stride = (size_t)gridDim.x * blockDim.x;

    for (size_t i = (size_t)blockIdx.x * blockDim.x + threadIdx.x;
         i < n4; i += stride) {
        const size_t e    = i * 4;           // element index within pass
        const size_t trel = e >> 13;         // / (B*D = 8192)
        const size_t r    = e & 8191;
        const uint4 w = *(const uint4*)(sw + ((trel >> 5) << 13) + r);
        const unsigned sh = (unsigned)trel & 31u;
        const float4 x = ip[i];
        float4 o;
        o.x = __fadd_rn((float)((w.x >> sh) & 1u), x.x);
        o.y = __fadd_rn((float)((w.y >> sh) & 1u), x.y);
        o.z = __fadd_rn((float)((w.z >> sh) & 1u), x.z);
        o.w = __fadd_rn((float)((w.w >> sh) & 1u), x.w);
        op[i] = o;
    }
}

// ---------------------------------------------------------------------------
// Pass-windowed driver. Spike words overlay the (dead-after-dw_conv) Yw
// region — no extra ws needed. L from ws_size (launch-time constant).
// ---------------------------------------------------------------------------
extern "C" void kernel_launch(void* const* d_in, const int* in_sizes, int n_in,
                              void* d_out, int out_size, void* d_ws, size_t ws_size,
                              hipStream_t stream)
{
    const float* inp  = (const float*)d_in[0];   // (T,B,D)
    const float* w_pw = (const float*)d_in[1];   // (D,D)
    const float* b_pw = (const float*)d_in[2];   // (D)
    const float* w_dw = (const float*)d_in[3];   // (D,K)
    float* out = (float*)d_out;

    auto need = [](int L) -> size_t {
        int ntw = (L + 30 > T_DIM) ? T_DIM : (L + 30);
        return ((size_t)ntw + (size_t)L + 1) * (B_DIM * D_DIM * sizeof(float));
    };
    int L = 64;
    if      (ws_size >= need(1024)) L = 1024;
    else if (ws_size >= need(512))  L = 512;
    else if (ws_size >= need(256))  L = 256;
    else if (ws_size >= need(128))  L = 128;

    const int NTWmax = (L + 30 > T_DIM) ? T_DIM : (L + 30);
    float* Yw  = (float*)d_ws;
    float* Zw  = Yw + (size_t)NTWmax * B_DIM * D_DIM;
    float* vst = Zw + (size_t)L * B_DIM * D_DIM;
    unsigned* sw = (unsigned*)Yw;                // overlay: Yw dead after dw_conv

    const int P = T_DIM / L;
    for (int p = 0; p < P; ++p) {
        const int t0   = p * L;
        const int t1   = t0 + L;
        const int tau0 = (t0 - PAD > 0) ? (t0 - PAD) : 0;
        const int tau1 = (t1 + PAD < T_DIM) ? (t1 + PAD) : T_DIM;
        const int NTW  = tau1 - tau0;

        dim3 g1(D_DIM / 128, (NTW + 127) / 128, B_DIM);
        pw_gemm<<<g1, 256, 0, stream>>>(inp, w_pw, b_pw, Yw, tau0, tau1, NTW);

        dim3 g2(L / 8, B_DIM);
        dw_conv<<<g2, 512, 0, stream>>>(Yw, w_dw, Zw, t0, tau0, NTW);

        lif_scan<<<128, 64, 0, stream>>>(Zw, sw, vst, L, p == 0);

        spike_add<<<2048, 256, 0, stream>>>(sw, inp, out, t0, L);
    }
}